// Round 1
// baseline (866.037 us; speedup 1.0000x reference)
//
#include <hip/hip_runtime.h>

typedef __bf16 bf16x8 __attribute__((ext_vector_type(8)));
typedef float  f32x4  __attribute__((ext_vector_type(4)));

// ---------- problem constants ----------
// E=40, GLOB=64, LOC=32, NSYM=16, NKPS=39, B=1, N=4096, D_IN=99
// LAYER_DIMS (di,do): (99,200)(200,200)(200,200)(200,101)(200,200)x5... skip at l=4
constexpr int DIL[9]   = {99,200,200,200,200,200,200,200,200};
constexpr int DOL[9]   = {200,200,200,101,200,200,200,200,1};
constexpr int KPADL[9] = {128,224,224,224,256,224,224,224,224}; // K padded to 32; L4 split-concat remapped to 256
constexpr int NPADL[9] = {208,208,208,112,208,208,208,208,16};  // out channels padded to 16
constexpr int KTL[9]   = {4,7,7,7,8,7,7,7,7};
constexpr int NTL[9]   = {13,13,13,7,13,13,13,13,1};
constexpr long long WOFFL[9] = {0,638976,1757184,2875392,3477504,4755456,5873664,6991872,8110080}; // elems, 24 members each
constexpr int BOFFL[9] = {0,4992,9984,14976,17664,22656,27648,32640,37632}; // f32 elems

// workspace layout (bytes)
constexpr size_t WS_ANCH = 0;       // 120 f32 (anch_bg 40x3, row39=0)
constexpr size_t WS_BIAS = 512;     // 38016 f32 padded biases
constexpr size_t WS_W    = 152576;  // 8,196,096 bf16 packed weights (~15.6MB)

__device__ __forceinline__ unsigned short f2bf(float f) {
  union { float f; unsigned u; } v; v.f = f;
  unsigned r = v.u + 0x7fffu + ((v.u >> 16) & 1u);   // RTNE
  return (unsigned short)(r >> 16);
}

__device__ __forceinline__ float sp100(float x) {
  // softplus(100x)/100 = max(x,0) + log(1+exp(-|100x|))/100
  float t = 100.f * x;
  float e = __expf(-fabsf(t));
  return fmaxf(x, 0.f) + 0.01f * __logf(1.f + e);
}

// ---------- weight/bias pack: f32 -> padded bf16 [m][o][k], zeros in pads ----------
template<int L>
__global__ void pack_k(const float* __restrict__ ew, const float* __restrict__ eb,
                       unsigned short* __restrict__ wout, float* __restrict__ bout) {
  constexpr int DI = DIL[L], DO = DOL[L], KP = KPADL[L], NP = NPADL[L];
  constexpr int WTOT = 24 * NP * KP;
  constexpr int TOT  = WTOT + 24 * NP;
  constexpr float SC = (L == 4) ? 0.70710678118654752f : 1.0f; // fold skip 1/sqrt(2) into W4
  int idx = blockIdx.x * 256 + threadIdx.x;
  if (idx < WTOT) {
    int m = idx / (NP * KP);
    int r = idx - m * (NP * KP);
    int o = r / KP;
    int k = r - o * KP;
    float v = 0.f;
    if (o < DO) {
      int ks;
      if constexpr (L == 4) ks = (k < 128) ? (k < 101 ? k : -1) : (k < 227 ? k - 27 : -1); // 101+(k-128)
      else                  ks = (k < DI) ? k : -1;
      if (ks >= 0) v = ew[((long)m * DO + o) * DI + ks] * SC;
    }
    wout[idx] = f2bf(v);
  } else if (idx < TOT) {
    int b = idx - WTOT;
    int m = b / NP, o = b - m * NP;
    bout[b] = (o < DO) ? eb[m * DO + o] : 0.f;
  }
}

// ---------- anchor MLP (tiny) + pred zero-init ----------
__global__ void anchors_k(const float* __restrict__ lat, const float* __restrict__ ac,
                          const float* __restrict__ pw0, const float* __restrict__ pb0,
                          const float* __restrict__ pw1, const float* __restrict__ pb1,
                          const float* __restrict__ pw2, const float* __restrict__ pb2,
                          float* __restrict__ wsAnch, float* __restrict__ outAnch,
                          float* __restrict__ pred) {
  __shared__ float g[64], h1[256], h2[256];
  int t = threadIdx.x;
  for (int i = t; i < 4096; i += 256) pred[i] = 0.f;   // pred accumulators (d_out poisoned each call)
  if (t < 64) g[t] = lat[t];                           // lat_rep[0,0,:64]
  __syncthreads();
  { float s = pb0[t]; for (int i = 0; i < 64;  ++i) s += g[i]  * pw0[i*256 + t]; h1[t] = fmaxf(s, 0.f); }
  __syncthreads();
  { float s = pb1[t]; for (int i = 0; i < 256; ++i) s += h1[i] * pw1[i*256 + t]; h2[t] = fmaxf(s, 0.f); }
  __syncthreads();
  if (t < 117) {
    float s = pb2[t];
    for (int i = 0; i < 256; ++i) s += h2[i] * pw2[i*117 + t];
    s += ac[t];
    wsAnch[t] = s; outAnch[t] = s;
  } else if (t < 120) {
    wsAnch[t] = 0.f;  // background "anchor" row = 0
  }
}

// ---------- fused ensemble MLP ----------
template<int L>
__device__ __forceinline__ void layer(int lane, int wid, int m,
    const unsigned short (*__restrict__ Xin)[232], unsigned short (*__restrict__ Xout)[232],
    const bf16x8* x0f, const unsigned short* __restrict__ Wp, const float* __restrict__ Bp,
    float* __restrict__ sdfS)
{
  constexpr int KT = KTL[L], NT = NTL[L], KP = KPADL[L], NP = NPADL[L];
  const unsigned short* Wm = Wp + WOFFL[L] + (long)m * (NP * KP);
  const float* Bm = Bp + BOFFL[L] + m * NP;
  const int l15 = lane & 15;
  const int kc  = (lane >> 4) * 8;
  const int arow = wid * 16 + l15;
  f32x4 acc[NT];
#pragma unroll
  for (int i = 0; i < NT; ++i) acc[i] = f32x4{0.f, 0.f, 0.f, 0.f};
#pragma unroll
  for (int kt = 0; kt < KT; ++kt) {
    bf16x8 a;
    if constexpr (L == 0) {
      a = x0f[kt];
    } else if constexpr (L == 4) {
      if (kt >= 4) a = x0f[kt - 4];                          // skip-connection part (inp_net)
      else         a = *(const bf16x8*)&Xin[arow][kt*32 + kc];
    } else {
      a = *(const bf16x8*)&Xin[arow][kt*32 + kc];
    }
    const unsigned short* wb = Wm + (long)l15 * KP + kt * 32 + kc;
#pragma unroll
    for (int nt = 0; nt < NT; ++nt) {
      bf16x8 b = *(const bf16x8*)(wb + (long)nt * 16 * KP);  // B[k][n] = W[n][k], 8 contig k per lane
      acc[nt] = __builtin_amdgcn_mfma_f32_16x16x32_bf16(a, b, acc[nt], 0, 0, 0);
    }
  }
  const int rb = (lane >> 4) * 4;   // C/D: col=lane&15, row=(lane>>4)*4+reg  [m89/m91]
#pragma unroll
  for (int nt = 0; nt < NT; ++nt) {
    int col = nt * 16 + l15;
    float bias = Bm[col];
#pragma unroll
    for (int r = 0; r < 4; ++r) {
      float v = acc[nt][r] + bias;
      if constexpr (L < 8) {
        v = sp100(v);
        Xout[wid * 16 + rb + r][col] = f2bf(v);
      } else {
        if (l15 == 0) sdfS[wid * 16 + rb + r] = v;
      }
    }
  }
}

__global__ __launch_bounds__(256, 2) void mlp_k(
    const float* __restrict__ xyz, const float* __restrict__ lat,
    const float* __restrict__ anch, const unsigned short* __restrict__ Wp,
    const float* __restrict__ Bp, float* __restrict__ pred)
{
  __shared__ __align__(16) unsigned short XB[64][232];  // stride 232 bf16 = 116 dw = 20 mod 32 -> <=2-way
  __shared__ __align__(16) unsigned short XC[64][232];
  __shared__ float anchS[120];
  __shared__ float sdfS[64];

  const int t = threadIdx.x;
  const int lane = t & 63;
  const int wid  = t >> 6;
  const int e  = blockIdx.x % 40;          // member-major -> member<->XCD affinity for L2 weight reuse
  const int pt = blockIdx.x / 40;
  const int n0 = pt * 64;
  const int m  = (e < 32) ? (e >> 1) : (e - 16);
  const float mir = (e < 32 && (e & 1)) ? -1.f : 1.f;

  { // zero LDS once: padded cols must never contain NaN bit patterns (garbage*0 in MFMA)
    unsigned* pB = (unsigned*)&XB[0][0];
    unsigned* pC = (unsigned*)&XC[0][0];
    for (int i = t; i < 7424; i += 256) { pB[i] = 0u; pC[i] = 0u; }
    if (t < 120) anchS[t] = anch[t];
  }
  __syncthreads();

  // stage inp_net (99 ch) for 64 points into XB, coalesced over channels
  const float ax = anchS[e*3+0], ay = anchS[e*3+1], az = anchS[e*3+2];
  for (int it = 0; it < 32; ++it) {
    int row = it * 2 + (t >> 7);
    int c = t & 127;
    long n = n0 + row;
    if (c < 99) {
      float v;
      if (c >= 67)      v = lat[n*1344 + 64 + e*32 + (c - 67)];
      else if (c >= 3)  v = lat[n*1344 + (c - 3)];
      else {
        v = xyz[n*3 + c] - ((c == 0) ? ax : (c == 1) ? ay : az);
        if (c == 0) v *= mir;
      }
      XB[row][c] = f2bf(v);
    }
  }
  __syncthreads();

  // park layer-0 input fragments in VGPRs (reused by skip at L4)
  bf16x8 x0f[4];
  {
    int arow = wid * 16 + (lane & 15);
    int kc = (lane >> 4) * 8;
#pragma unroll
    for (int k = 0; k < 4; ++k) x0f[k] = *(const bf16x8*)&XB[arow][k*32 + kc];
  }
  __syncthreads();

  layer<0>(lane, wid, m, XC, XB, x0f, Wp, Bp, nullptr); __syncthreads();
  layer<1>(lane, wid, m, XB, XC, x0f, Wp, Bp, nullptr); __syncthreads();
  layer<2>(lane, wid, m, XC, XB, x0f, Wp, Bp, nullptr); __syncthreads();
  layer<3>(lane, wid, m, XB, XC, x0f, Wp, Bp, nullptr); __syncthreads();
  layer<4>(lane, wid, m, XC, XB, x0f, Wp, Bp, nullptr); __syncthreads();
  layer<5>(lane, wid, m, XB, XC, x0f, Wp, Bp, nullptr); __syncthreads();
  layer<6>(lane, wid, m, XC, XB, x0f, Wp, Bp, nullptr); __syncthreads();
  layer<7>(lane, wid, m, XB, XC, x0f, Wp, Bp, nullptr); __syncthreads();
  layer<8>(lane, wid, m, XC, XB, x0f, Wp, Bp, sdfS);    __syncthreads();

  // distance softmax over 40 anchors (f32) + atomic blend
  if (t < 64) {
    long n = n0 + t;
    float px = xyz[n*3], py = xyz[n*3+1], pz = xyz[n*3+2];
    float den = 1e-6f + __expf(-20.f);            // background term exp(-0.2/0.01)
    for (int j = 0; j < 39; ++j) {
      float dx = anchS[j*3] - px, dy = anchS[j*3+1] - py, dz = anchS[j*3+2] - pz;
      float d = sqrtf(dx*dx + dy*dy + dz*dz) + 1e-5f;
      den += __expf(-100.f * d * d);
    }
    float num;
    if (e == 39) num = __expf(-20.f);
    else {
      float dx = anchS[e*3] - px, dy = anchS[e*3+1] - py, dz = anchS[e*3+2] - pz;
      float d = sqrtf(dx*dx + dy*dy + dz*dz) + 1e-5f;
      num = __expf(-100.f * d * d);
    }
    atomicAdd(&pred[n], (num / den) * sdfS[t]);
  }
}

extern "C" void kernel_launch(void* const* d_in, const int* in_sizes, int n_in,
                              void* d_out, int out_size, void* d_ws, size_t ws_size,
                              hipStream_t stream) {
  const float* xyz = (const float*)d_in[0];
  const float* lat = (const float*)d_in[1];
  const float* ac  = (const float*)d_in[2];
  const float* pw0 = (const float*)d_in[3]; const float* pb0 = (const float*)d_in[4];
  const float* pw1 = (const float*)d_in[5]; const float* pb1 = (const float*)d_in[6];
  const float* pw2 = (const float*)d_in[7]; const float* pb2 = (const float*)d_in[8];
  const float* ew[9]; const float* eb[9];
  for (int l = 0; l < 9; ++l) { ew[l] = (const float*)d_in[9 + 2*l]; eb[l] = (const float*)d_in[10 + 2*l]; }

  float* out = (float*)d_out;                 // [0,4096) pred, [4096,4213) anch
  char* ws = (char*)d_ws;
  float* wsAnch = (float*)(ws + WS_ANCH);
  float* wsBias = (float*)(ws + WS_BIAS);
  unsigned short* wsW = (unsigned short*)(ws + WS_W);

  anchors_k<<<1, 256, 0, stream>>>(lat, ac, pw0, pb0, pw1, pb1, pw2, pb2,
                                   wsAnch, out + 4096, out);

#define LAUNCH_PACK(L) do { \
    constexpr int TOT = 24*NPADL[L]*KPADL[L] + 24*NPADL[L]; \
    pack_k<L><<<(TOT + 255)/256, 256, 0, stream>>>(ew[L], eb[L], wsW + WOFFL[L], wsBias + BOFFL[L]); \
  } while (0)
  LAUNCH_PACK(0); LAUNCH_PACK(1); LAUNCH_PACK(2); LAUNCH_PACK(3); LAUNCH_PACK(4);
  LAUNCH_PACK(5); LAUNCH_PACK(6); LAUNCH_PACK(7); LAUNCH_PACK(8);
#undef LAUNCH_PACK

  mlp_k<<<2560, 256, 0, stream>>>(xyz, lat, wsAnch, wsW, wsBias, out);
}

// Round 3
// 733.579 us; speedup vs baseline: 1.1806x; 1.1806x over previous
//
#include <hip/hip_runtime.h>

typedef __bf16 bf16x8 __attribute__((ext_vector_type(8)));
typedef float  f32x4  __attribute__((ext_vector_type(4)));

// ---------- problem constants ----------
constexpr int DIL[9]   = {99,200,200,200,200,200,200,200,200};
constexpr int DOL[9]   = {200,200,200,101,200,200,200,200,1};
constexpr int KPADL[9] = {128,224,224,224,256,224,224,224,224}; // K padded to 32; L4 concat remapped
constexpr int NPADL[9] = {208,208,208,112,208,208,208,208,16};  // out channels padded to 16
constexpr int KTL[9]   = {4,7,7,7,8,7,7,7,7};
constexpr int NT0L[9]  = {7,7,7,4,7,7,7,7,1};   // N-tiles for wave-group ng=0
constexpr int NT1L[9]  = {6,6,6,3,6,6,6,6,0};   // N-tiles for wave-group ng=1
constexpr long long WOFFL[9] = {0,638976,1757184,2875392,3477504,4755456,5873664,6991872,8110080};
constexpr int BOFFL[9] = {0,4992,9984,14976,17664,22656,27648,32640,37632};

// workspace layout (bytes)
constexpr size_t WS_ANCH = 0;
constexpr size_t WS_BIAS = 512;
constexpr size_t WS_W    = 152576;

__device__ __forceinline__ unsigned short f2bf(float f) {
  union { float f; unsigned u; } v; v.f = f;
  unsigned r = v.u + 0x7fffu + ((v.u >> 16) & 1u);   // RTNE
  return (unsigned short)(r >> 16);
}

__device__ __forceinline__ float sp100(float x) {
  float e = __expf(-100.f * fabsf(x));
  return fmaxf(x, 0.f) + 0.01f * __logf(1.f + e);
}

// ---------- weight/bias pack: f32 -> padded bf16 [m][o][k], zeros in pads ----------
template<int L>
__global__ void pack_k(const float* __restrict__ ew, const float* __restrict__ eb,
                       unsigned short* __restrict__ wout, float* __restrict__ bout) {
  constexpr int DI = DIL[L], DO = DOL[L], KP = KPADL[L], NP = NPADL[L];
  constexpr int WTOT = 24 * NP * KP;
  constexpr int TOT  = WTOT + 24 * NP;
  constexpr float SC = (L == 4) ? 0.70710678118654752f : 1.0f;
  int idx = blockIdx.x * 256 + threadIdx.x;
  if (idx < WTOT) {
    int m = idx / (NP * KP);
    int r = idx - m * (NP * KP);
    int o = r / KP;
    int k = r - o * KP;
    float v = 0.f;
    if (o < DO) {
      int ks;
      if constexpr (L == 4) ks = (k < 128) ? (k < 101 ? k : -1) : (k < 227 ? k - 27 : -1);
      else                  ks = (k < DI) ? k : -1;
      if (ks >= 0) v = ew[((long)m * DO + o) * DI + ks] * SC;
    }
    wout[idx] = f2bf(v);
  } else if (idx < TOT) {
    int b = idx - WTOT;
    int m = b / NP, o = b - m * NP;
    bout[b] = (o < DO) ? eb[m * DO + o] : 0.f;
  }
}

// ---------- anchor MLP (tiny) + pred zero-init ----------
__global__ void anchors_k(const float* __restrict__ lat, const float* __restrict__ ac,
                          const float* __restrict__ pw0, const float* __restrict__ pb0,
                          const float* __restrict__ pw1, const float* __restrict__ pb1,
                          const float* __restrict__ pw2, const float* __restrict__ pb2,
                          float* __restrict__ wsAnch, float* __restrict__ outAnch,
                          float* __restrict__ pred) {
  __shared__ float g[64], h1[256], h2[256];
  int t = threadIdx.x;
  for (int i = t; i < 4096; i += 256) pred[i] = 0.f;
  if (t < 64) g[t] = lat[t];
  __syncthreads();
  { float s = pb0[t]; for (int i = 0; i < 64;  ++i) s += g[i]  * pw0[i*256 + t]; h1[t] = fmaxf(s, 0.f); }
  __syncthreads();
  { float s = pb1[t]; for (int i = 0; i < 256; ++i) s += h1[i] * pw1[i*256 + t]; h2[t] = fmaxf(s, 0.f); }
  __syncthreads();
  if (t < 117) {
    float s = pb2[t];
    for (int i = 0; i < 256; ++i) s += h2[i] * pw2[i*117 + t];
    s += ac[t];
    wsAnch[t] = s; outAnch[t] = s;
  } else if (t < 120) {
    wsAnch[t] = 0.f;
  }
}

// ---------- fused ensemble MLP ----------
// LDS activation layout: uint2 slot (g,p) = 4 bf16 channels [4g..4g+3] of point p,
// swizzled: idx = g*64 + (p ^ (g&15)).
__device__ __forceinline__ int xsw(int g, int p) { return g * 64 + (p ^ (g & 15)); }

template<int L> struct AF { bf16x8 a[2][(L == 4) ? 4 : KTL[L]]; };

template<int L>
__device__ __forceinline__ void layerA(int l15, int hi2, int mg,
    const uint2* __restrict__ X, const uint2* __restrict__ X0, AF<L>& af)
{
  constexpr int KTA = (L == 4) ? 4 : KTL[L];
  const uint2* __restrict__ src = (L == 0) ? X0 : X;
#pragma unroll
  for (int mf = 0; mf < 2; ++mf) {
    int p = mg * 32 + mf * 16 + l15;
#pragma unroll
    for (int kt = 0; kt < KTA; ++kt) {
      int g0 = (kt * 4 + hi2) * 2;
      uint2 q0 = src[xsw(g0,     p)];
      uint2 q1 = src[xsw(g0 + 1, p)];
      uint4 q = make_uint4(q0.x, q0.y, q1.x, q1.y);
      af.a[mf][kt] = *(bf16x8*)&q;
    }
  }
}

template<int L, int NTG, int NTB>
__device__ __forceinline__ void layerB(int l15, int hi2, int mg, int m,
    uint2* __restrict__ X, const uint2* __restrict__ X0,
    const unsigned short* __restrict__ Wp, const float* __restrict__ Bp,
    const AF<L>& af, float* __restrict__ sdfS)
{
  constexpr int KT = KTL[L], KP = KPADL[L], NP = NPADL[L];
  f32x4 acc[2][NTG];
#pragma unroll
  for (int mf = 0; mf < 2; ++mf)
#pragma unroll
    for (int nt = 0; nt < NTG; ++nt) acc[mf][nt] = f32x4{0.f, 0.f, 0.f, 0.f};

  const unsigned short* Wm = Wp + WOFFL[L] + (long)m * (NP * KP) + (long)l15 * KP + hi2 * 8;
#pragma unroll
  for (int kt = 0; kt < KT; ++kt) {
    bf16x8 av0, av1;
    if constexpr (L == 4) {
      if (kt >= 4) {   // skip-connection half: stream inp_net frags from X0 (never written -> no hazard)
        int g0 = ((kt - 4) * 4 + hi2) * 2;
        int p0 = mg * 32 + l15, p1 = mg * 32 + 16 + l15;
        uint2 q0 = X0[xsw(g0, p0)], q1 = X0[xsw(g0 + 1, p0)];
        uint4 qa = make_uint4(q0.x, q0.y, q1.x, q1.y); av0 = *(bf16x8*)&qa;
        q0 = X0[xsw(g0, p1)]; q1 = X0[xsw(g0 + 1, p1)];
        uint4 qb = make_uint4(q0.x, q0.y, q1.x, q1.y); av1 = *(bf16x8*)&qb;
      } else { av0 = af.a[0][kt]; av1 = af.a[1][kt]; }
    } else { av0 = af.a[0][kt]; av1 = af.a[1][kt]; }
    const unsigned short* wk = Wm + kt * 32;
#pragma unroll
    for (int nt = 0; nt < NTG; ++nt) {
      bf16x8 b = *(const bf16x8*)(wk + (long)((NTB + nt) * 16) * KP);
      // OPERAND SWAP (round-2 bugfix): compute W·X^T so D-fragment is
      // channel = hi2*4 + reg, point = l15 — matching the transposed LDS
      // epilogue below. Both operands share the same per-lane layout, so the
      // fragments load identically; only the argument order changes.
      acc[0][nt] = __builtin_amdgcn_mfma_f32_16x16x32_bf16(b, av0, acc[0][nt], 0, 0, 0);
      acc[1][nt] = __builtin_amdgcn_mfma_f32_16x16x32_bf16(b, av1, acc[1][nt], 0, 0, 0);
    }
  }

  const float* Bm = Bp + BOFFL[L] + m * NP;
#pragma unroll
  for (int nt = 0; nt < NTG; ++nt) {
    int c0 = (NTB + nt) * 16 + hi2 * 4;       // 4 consecutive channels = one uint2 group
    float4 bb = *(const float4*)(Bm + c0);
    int g = c0 >> 2;
#pragma unroll
    for (int mf = 0; mf < 2; ++mf) {
      int p = mg * 32 + mf * 16 + l15;
      float v0 = acc[mf][nt][0] + bb.x, v1 = acc[mf][nt][1] + bb.y;
      float v2 = acc[mf][nt][2] + bb.z, v3 = acc[mf][nt][3] + bb.w;
      if constexpr (L < 8) {
        v0 = sp100(v0); v1 = sp100(v1); v2 = sp100(v2); v3 = sp100(v3);
        uint2 w;
        w.x = (unsigned)f2bf(v0) | ((unsigned)f2bf(v1) << 16);
        w.y = (unsigned)f2bf(v2) | ((unsigned)f2bf(v3) << 16);
        X[xsw(g, p)] = w;
      } else {
        if (hi2 == 0) sdfS[p] = v0;   // channel 0 = (hi2=0, reg 0)
      }
    }
  }
}

__global__ __launch_bounds__(256, 3) void mlp_k(
    const float* __restrict__ xyz, const float* __restrict__ lat,
    const float* __restrict__ anch, const unsigned short* __restrict__ Wp,
    const float* __restrict__ Bp, float* __restrict__ pred)
{
  __shared__ uint2 X[56 * 64];    // 224 ch x 64 pts, 28.7 KB
  __shared__ uint2 X0[32 * 64];   // 128 ch x 64 pts (inp_net), 16.4 KB
  __shared__ float anchS[120];
  __shared__ float sdfS[64];

  const int t = threadIdx.x;
  const int lane = t & 63, wid = t >> 6;
  const int l15 = lane & 15, hi2 = lane >> 4;
  const int mg = wid & 1, ng = wid >> 1;    // 2 M-groups x 2 N-groups
  const int e  = blockIdx.x % 40;           // member<->XCD affinity
  const int pt = blockIdx.x / 40;
  const int n0 = pt * 64;
  const int m  = (e < 32) ? (e >> 1) : (e - 16);
  const float mir = (e < 32 && (e & 1)) ? -1.f : 1.f;

  // zero only never-written pad groups (they feed MFMA as operands against zero weights; must be finite)
  for (int i = 52 * 64 + t; i < 56 * 64; i += 256) X[i]  = make_uint2(0u, 0u);
  for (int i = 24 * 64 + t; i < 32 * 64; i += 256) X0[i] = make_uint2(0u, 0u);
  if (t < 120) anchS[t] = anch[t];
  __syncthreads();

  // stage inp_net (99 ch) for 64 points into X0 (coalesced reads over channels)
  const float ax = anchS[e * 3], ay = anchS[e * 3 + 1], az = anchS[e * 3 + 2];
  for (int it = 0; it < 32; ++it) {
    int row = it * 2 + (t >> 7);
    int c = t & 127;
    long n = n0 + row;
    if (c < 99) {
      float v;
      if (c >= 67)      v = lat[n * 1344 + 64 + e * 32 + (c - 67)];
      else if (c >= 3)  v = lat[n * 1344 + (c - 3)];
      else {
        v = xyz[n * 3 + c] - ((c == 0) ? ax : (c == 1) ? ay : az);
        if (c == 0) v *= mir;
      }
      int g = c >> 2;
      ((unsigned short*)&X0[xsw(g, row)])[c & 3] = f2bf(v);
    }
  }
  __syncthreads();

#define RUN_LAYER(L) do {                                                       \
    AF<L> af;                                                                   \
    layerA<L>(l15, hi2, mg, X, X0, af);                                         \
    __syncthreads();                                                            \
    if (ng == 0) layerB<L, NT0L[L], 0>(l15, hi2, mg, m, X, X0, Wp, Bp, af, sdfS); \
    else { if constexpr (NT1L[L] > 0)                                           \
           layerB<L, (NT1L[L] > 0 ? NT1L[L] : 1), NT0L[L]>(l15, hi2, mg, m, X, X0, Wp, Bp, af, sdfS); } \
    __syncthreads();                                                            \
  } while (0)

  RUN_LAYER(0); RUN_LAYER(1); RUN_LAYER(2); RUN_LAYER(3); RUN_LAYER(4);
  RUN_LAYER(5); RUN_LAYER(6); RUN_LAYER(7); RUN_LAYER(8);
#undef RUN_LAYER

  // distance softmax over 40 anchors + atomic blend
  if (t < 64) {
    long n = n0 + t;
    float px = xyz[n * 3], py = xyz[n * 3 + 1], pz = xyz[n * 3 + 2];
    float den = 1e-6f + __expf(-20.f);
    for (int j = 0; j < 39; ++j) {
      float dx = anchS[j * 3] - px, dy = anchS[j * 3 + 1] - py, dz = anchS[j * 3 + 2] - pz;
      float d = sqrtf(dx * dx + dy * dy + dz * dz) + 1e-5f;
      den += __expf(-100.f * d * d);
    }
    float num;
    if (e == 39) num = __expf(-20.f);
    else {
      float dx = anchS[e * 3] - px, dy = anchS[e * 3 + 1] - py, dz = anchS[e * 3 + 2] - pz;
      float d = sqrtf(dx * dx + dy * dy + dz * dz) + 1e-5f;
      num = __expf(-100.f * d * d);
    }
    atomicAdd(&pred[n], (num / den) * sdfS[t]);
  }
}

extern "C" void kernel_launch(void* const* d_in, const int* in_sizes, int n_in,
                              void* d_out, int out_size, void* d_ws, size_t ws_size,
                              hipStream_t stream) {
  const float* xyz = (const float*)d_in[0];
  const float* lat = (const float*)d_in[1];
  const float* ac  = (const float*)d_in[2];
  const float* pw0 = (const float*)d_in[3]; const float* pb0 = (const float*)d_in[4];
  const float* pw1 = (const float*)d_in[5]; const float* pb1 = (const float*)d_in[6];
  const float* pw2 = (const float*)d_in[7]; const float* pb2 = (const float*)d_in[8];
  const float* ew[9]; const float* eb[9];
  for (int l = 0; l < 9; ++l) { ew[l] = (const float*)d_in[9 + 2*l]; eb[l] = (const float*)d_in[10 + 2*l]; }

  float* out = (float*)d_out;                 // [0,4096) pred, [4096,4213) anch
  char* ws = (char*)d_ws;
  float* wsAnch = (float*)(ws + WS_ANCH);
  float* wsBias = (float*)(ws + WS_BIAS);
  unsigned short* wsW = (unsigned short*)(ws + WS_W);

  anchors_k<<<1, 256, 0, stream>>>(lat, ac, pw0, pb0, pw1, pb1, pw2, pb2,
                                   wsAnch, out + 4096, out);

#define LAUNCH_PACK(L) do { \
    constexpr int TOT = 24*NPADL[L]*KPADL[L] + 24*NPADL[L]; \
    pack_k<L><<<(TOT + 255)/256, 256, 0, stream>>>(ew[L], eb[L], wsW + WOFFL[L], wsBias + BOFFL[L]); \
  } while (0)
  LAUNCH_PACK(0); LAUNCH_PACK(1); LAUNCH_PACK(2); LAUNCH_PACK(3); LAUNCH_PACK(4);
  LAUNCH_PACK(5); LAUNCH_PACK(6); LAUNCH_PACK(7); LAUNCH_PACK(8);
#undef LAUNCH_PACK

  mlp_k<<<2560, 256, 0, stream>>>(xyz, lat, wsAnch, wsW, wsBias, out);
}